// Round 5
// baseline (323.017 us; speedup 1.0000x reference)
//
#include <hip/hip_runtime.h>

// FiringRateModel, z-recurrence, TWO phase-staggered chain-groups per wave.
//   sigma_t = d*sigma_{t-1} + c_t*(d*aw) + f_{t-1}*(d*bw)
//   z_{t+1} = Sum(sigma_t) + c_{t+1}*SAu + f_t*SBu
//   f_t = 200*tanh(max(poly(z_t/100 - g_b/100), 0))
// Layout: 16 lanes/chain (one DPP row), 4 states/lane. Each wave advances
// two independent groups of 4 chains (G0 rows, G1 rows) in one instruction
// stream -> G1's ops fill G0's dependency stalls and vice versa.
// 1024 waves = 1/SIMD. Activation folds -2*log2(e) into coeffs (fmin flip).

#define TT 2048
#define BB 8192

typedef float v2f __attribute__((ext_vector_type(2)));

__device__ __forceinline__ float dpp_add_x1(float z) {
    float o;
    asm("v_add_f32 %0, %1, %2 quad_perm:[1,0,3,2] row_mask:0xf bank_mask:0xf"
        : "=v"(o) : "v"(z), "v"(z));
    return o;
}
__device__ __forceinline__ float dpp_add_x2(float z) {
    float o;
    asm("v_add_f32 %0, %1, %2 quad_perm:[2,3,0,1] row_mask:0xf bank_mask:0xf"
        : "=v"(o) : "v"(z), "v"(z));
    return o;
}
__device__ __forceinline__ float dpp_add_r4(float z) {
    float o;
    asm("v_add_f32 %0, %1, %2 row_ror:4 row_mask:0xf bank_mask:0xf"
        : "=v"(o) : "v"(z), "v"(z));
    return o;
}
__device__ __forceinline__ float dpp_add_r8(float z) {
    float o;
    asm("v_add_f32 %0, %1, %2 row_ror:8 row_mask:0xf bank_mask:0xf"
        : "=v"(o) : "v"(z), "v"(z));
    return o;
}
__device__ __forceinline__ float allreduce16(float z) {
    z = dpp_add_x1(z);
    z = dpp_add_x2(z);
    z = dpp_add_r4(z);
    z = dpp_add_r8(z);
    return z;
}

// One time step for BOTH groups, A/B lines interleaved for the scheduler.
// f ping-pong per group via FinX/FoutX macro args.
#define STEP2(cA, cAn, cB, cBn, so, FinA, FoutA, FinB, FoutB) do {      \
    float xxA = fmaf(zA, 0.01f, ngb01);                                 \
    float xxB = fmaf(zB, 0.01f, ngb01);                                 \
    float x2A = xxA * xxA;                                              \
    float x2B = xxB * xxB;                                              \
    float t1A = fmaf(k5, xxA, k4);                                      \
    float t1B = fmaf(k5, xxB, k4);                                      \
    float t2A = fmaf(k3, xxA, k2);                                      \
    float t2B = fmaf(k3, xxB, k2);                                      \
    float t3A = fmaf(k1, xxA, k0);                                      \
    float t3B = fmaf(k1, xxB, k0);                                      \
    float plA = fmaf(t1A, x2A, t2A);                                    \
    float plB = fmaf(t1B, x2B, t2B);                                    \
    plA = fmaf(plA, x2A, t3A);                                          \
    plB = fmaf(plB, x2B, t3B);                                          \
    plA = fminf(plA, 0.0f);          /* coeffs carry -2*log2e */        \
    plB = fminf(plB, 0.0f);                                             \
    float eeA = __builtin_amdgcn_exp2f(plA);                            \
    float eeB = __builtin_amdgcn_exp2f(plB);                            \
    FoutA = fmaf(eeA, -200.0f, 200.0f) * __builtin_amdgcn_rcpf(1.0f + eeA); \
    FoutB = fmaf(eeB, -200.0f, 200.0f) * __builtin_amdgcn_rcpf(1.0f + eeB); \
    v2f fa2 = { FinA, FinA }, ca2 = { (cA), (cA) };                     \
    v2f fb2 = { FinB, FinB }, cb2 = { (cB), (cB) };                     \
    sgA0 = __builtin_elementwise_fma(d01, sgA0,                         \
             __builtin_elementwise_fma(ca2, A01, fa2 * B01));           \
    sgB0 = __builtin_elementwise_fma(d01, sgB0,                         \
             __builtin_elementwise_fma(cb2, A01, fb2 * B01));           \
    sgA1 = __builtin_elementwise_fma(d23, sgA1,                         \
             __builtin_elementwise_fma(ca2, A23, fa2 * B23));           \
    sgB1 = __builtin_elementwise_fma(d23, sgB1,                         \
             __builtin_elementwise_fma(cb2, A23, fb2 * B23));           \
    v2f ssA = sgA0 + sgA1;                                              \
    v2f ssB = sgB0 + sgB1;                                              \
    float SrA = allreduce16(ssA.x + ssA.y);                             \
    float SrB = allreduce16(ssB.x + ssB.y);                             \
    zA = fmaf(FoutA, SBu, fmaf((cAn), SAu, SrA));                       \
    zB = fmaf(FoutB, SBu, fmaf((cBn), SAu, SrB));                       \
    if (g == 0) {                                                       \
        outA[obase + (so) * BB] = FoutA;                                \
        outB[obase + (so) * BB] = FoutB;                                \
    }                                                                   \
} while (0)

__global__ __launch_bounds__(256, 1) void frm_kernel(
    const float* __restrict__ cur, const float* __restrict__ fs0,
    const float* __restrict__ av,  const float* __restrict__ bv,
    const float* __restrict__ wv,  const float* __restrict__ dsv,
    const float* __restrict__ pcv, const float* __restrict__ gbv,
    float* __restrict__ outp)
{
    const int tid  = blockIdx.x * 256 + threadIdx.x;
    const int wave = tid >> 6;                 // 0..1023
    const int row  = (threadIdx.x & 63) >> 4;  // 0..3 (DPP row within wave)
    const int g    = threadIdx.x & 15;         // lane within row

    const int cA = wave * 8 + row;             // group-0 chain
    const int cB = wave * 8 + 4 + row;         // group-1 chain

    const int n0 = g * 4;                      // lane's 4 state indices (shared)
    const float w0 = wv[n0+0], w1 = wv[n0+1], w2 = wv[n0+2], w3 = wv[n0+3];
    const float dk0 = 1.0f - dsv[n0+0], dk1 = 1.0f - dsv[n0+1];
    const float dk2 = 1.0f - dsv[n0+2], dk3 = 1.0f - dsv[n0+3];
    const float ak0 = av[n0+0]*w0, ak1 = av[n0+1]*w1;
    const float ak2 = av[n0+2]*w2, ak3 = av[n0+3]*w3;
    const float bk0 = 1000.0f*bv[n0+0]*w0, bk1 = 1000.0f*bv[n0+1]*w1;
    const float bk2 = 1000.0f*bv[n0+2]*w2, bk3 = 1000.0f*bv[n0+3]*w3;

    const v2f d01 = {dk0, dk1}, d23 = {dk2, dk3};
    const v2f A01 = {dk0*ak0, dk1*ak1}, A23 = {dk2*ak2, dk3*ak3};
    const v2f B01 = {dk0*bk0, dk1*bk1}, B23 = {dk2*bk2, dk3*bk3};

    const float SAu = allreduce16((ak0+ak1)+(ak2+ak3));
    const float SBu = allreduce16((bk0+bk1)+(bk2+bk3));

    // activation coeffs: squared, scaled by -2*log2(e) (fmax -> fmin flip)
    const float M = -2.8853900817779268f;
    const float k0 = M*pcv[0]*pcv[0], k1 = M*pcv[1]*pcv[1], k2 = M*pcv[2]*pcv[2];
    const float k3 = M*pcv[3]*pcv[3], k4 = M*pcv[4]*pcv[4], k5 = M*pcv[5]*pcv[5];
    const float ngb01 = -gbv[0] * 0.01f;

    float fA0 = fs0[cA], fA1;                  // group-0 f ping-pong
    float fB0 = fs0[cB], fB1;                  // group-1 f ping-pong
    v2f sgA0 = {0,0}, sgA1 = {0,0};
    v2f sgB0 = {0,0}, sgB1 = {0,0};

    const float* cptA = cur + cA;
    const float* cptB = cur + cB;
    float* outA = outp + cA;
    float* outB = outp + cB;

    // distance-16 prefetch pipeline per group, two 8-wide banks
    float PA0 = cptA[0*BB], PA1 = cptA[1*BB], PA2 = cptA[2*BB], PA3 = cptA[3*BB];
    float PA4 = cptA[4*BB], PA5 = cptA[5*BB], PA6 = cptA[6*BB], PA7 = cptA[7*BB];
    float PB0 = cptB[0*BB], PB1 = cptB[1*BB], PB2 = cptB[2*BB], PB3 = cptB[3*BB];
    float PB4 = cptB[4*BB], PB5 = cptB[5*BB], PB6 = cptB[6*BB], PB7 = cptB[7*BB];
    float QA0 = cptA[8*BB], QA1 = cptA[9*BB], QA2 = cptA[10*BB], QA3 = cptA[11*BB];
    float QA4 = cptA[12*BB], QA5 = cptA[13*BB], QA6 = cptA[14*BB], QA7 = cptA[15*BB];
    float QB0 = cptB[8*BB], QB1 = cptB[9*BB], QB2 = cptB[10*BB], QB3 = cptB[11*BB];
    float QB4 = cptB[12*BB], QB5 = cptB[13*BB], QB6 = cptB[14*BB], QB7 = cptB[15*BB];

    // z_0 = c_0*SAu + fs0*SBu  (sigma_{-1} = 0)
    float zA = fmaf(fA0, SBu, PA0 * SAu);
    float zB = fmaf(fB0, SBu, PB0 * SAu);

    int obase = 0;
    for (int t = 0; t + 32 <= TT; t += 16) {
        STEP2(PA0, PA1, PB0, PB1, 0, fA0, fA1, fB0, fB1);
        STEP2(PA1, PA2, PB1, PB2, 1, fA1, fA0, fB1, fB0);
        STEP2(PA2, PA3, PB2, PB3, 2, fA0, fA1, fB0, fB1);
        STEP2(PA3, PA4, PB3, PB4, 3, fA1, fA0, fB1, fB0);
        STEP2(PA4, PA5, PB4, PB5, 4, fA0, fA1, fB0, fB1);
        STEP2(PA5, PA6, PB5, PB6, 5, fA1, fA0, fB1, fB0);
        STEP2(PA6, PA7, PB6, PB7, 6, fA0, fA1, fB0, fB1);
        STEP2(PA7, QA0, PB7, QB0, 7, fA1, fA0, fB1, fB0);
        PA0 = cptA[obase + 16*BB]; PA1 = cptA[obase + 17*BB];
        PA2 = cptA[obase + 18*BB]; PA3 = cptA[obase + 19*BB];
        PA4 = cptA[obase + 20*BB]; PA5 = cptA[obase + 21*BB];
        PA6 = cptA[obase + 22*BB]; PA7 = cptA[obase + 23*BB];
        PB0 = cptB[obase + 16*BB]; PB1 = cptB[obase + 17*BB];
        PB2 = cptB[obase + 18*BB]; PB3 = cptB[obase + 19*BB];
        PB4 = cptB[obase + 20*BB]; PB5 = cptB[obase + 21*BB];
        PB6 = cptB[obase + 22*BB]; PB7 = cptB[obase + 23*BB];
        STEP2(QA0, QA1, QB0, QB1, 8, fA0, fA1, fB0, fB1);
        STEP2(QA1, QA2, QB1, QB2, 9, fA1, fA0, fB1, fB0);
        STEP2(QA2, QA3, QB2, QB3, 10, fA0, fA1, fB0, fB1);
        STEP2(QA3, QA4, QB3, QB4, 11, fA1, fA0, fB1, fB0);
        STEP2(QA4, QA5, QB4, QB5, 12, fA0, fA1, fB0, fB1);
        STEP2(QA5, QA6, QB5, QB6, 13, fA1, fA0, fB1, fB0);
        STEP2(QA6, QA7, QB6, QB7, 14, fA0, fA1, fB0, fB1);
        STEP2(QA7, PA0, QB7, PB0, 15, fA1, fA0, fB1, fB0);
        QA0 = cptA[obase + 24*BB]; QA1 = cptA[obase + 25*BB];
        QA2 = cptA[obase + 26*BB]; QA3 = cptA[obase + 27*BB];
        QA4 = cptA[obase + 28*BB]; QA5 = cptA[obase + 29*BB];
        QA6 = cptA[obase + 30*BB]; QA7 = cptA[obase + 31*BB];
        QB0 = cptB[obase + 24*BB]; QB1 = cptB[obase + 25*BB];
        QB2 = cptB[obase + 26*BB]; QB3 = cptB[obase + 27*BB];
        QB4 = cptB[obase + 28*BB]; QB5 = cptB[obase + 29*BB];
        QB6 = cptB[obase + 30*BB]; QB7 = cptB[obase + 31*BB];
        obase += 16 * BB;
    }
    // epilogue: last 16 steps entirely from registers
    STEP2(PA0, PA1, PB0, PB1, 0, fA0, fA1, fB0, fB1);
    STEP2(PA1, PA2, PB1, PB2, 1, fA1, fA0, fB1, fB0);
    STEP2(PA2, PA3, PB2, PB3, 2, fA0, fA1, fB0, fB1);
    STEP2(PA3, PA4, PB3, PB4, 3, fA1, fA0, fB1, fB0);
    STEP2(PA4, PA5, PB4, PB5, 4, fA0, fA1, fB0, fB1);
    STEP2(PA5, PA6, PB5, PB6, 5, fA1, fA0, fB1, fB0);
    STEP2(PA6, PA7, PB6, PB7, 6, fA0, fA1, fB0, fB1);
    STEP2(PA7, QA0, PB7, QB0, 7, fA1, fA0, fB1, fB0);
    STEP2(QA0, QA1, QB0, QB1, 8, fA0, fA1, fB0, fB1);
    STEP2(QA1, QA2, QB1, QB2, 9, fA1, fA0, fB1, fB0);
    STEP2(QA2, QA3, QB2, QB3, 10, fA0, fA1, fB0, fB1);
    STEP2(QA3, QA4, QB3, QB4, 11, fA1, fA0, fB1, fB0);
    STEP2(QA4, QA5, QB4, QB5, 12, fA0, fA1, fB0, fB1);
    STEP2(QA5, QA6, QB5, QB6, 13, fA1, fA0, fB1, fB0);
    STEP2(QA6, QA7, QB6, QB7, 14, fA0, fA1, fB0, fB1);
    STEP2(QA7, 0.0f, QB7, 0.0f, 15, fA1, fA0, fB1, fB0);
}

extern "C" void kernel_launch(void* const* d_in, const int* in_sizes, int n_in,
                              void* d_out, int out_size, void* d_ws, size_t ws_size,
                              hipStream_t stream) {
    const float* cur = (const float*)d_in[0];
    const float* fs0 = (const float*)d_in[1];
    const float* a   = (const float*)d_in[2];
    const float* b   = (const float*)d_in[3];
    const float* w   = (const float*)d_in[4];
    const float* ds  = (const float*)d_in[5];
    const float* pc  = (const float*)d_in[6];
    const float* gb  = (const float*)d_in[7];
    float* out = (float*)d_out;

    const int threads = 256;
    const int grid = (BB * 8) / threads;   // 256 blocks = 1024 waves = 1/SIMD
    frm_kernel<<<grid, threads, 0, stream>>>(cur, fs0, a, b, w, ds, pc, gb, out);
}

// Round 6
// 215.516 us; speedup vs baseline: 1.4988x; 1.4988x over previous
//
#include <hip/hip_runtime.h>

// FiringRateModel, xx-recurrence, 8 lanes/chain, 8 states/lane (R3 layout).
//   sigma'_t = d*sigma'_{t-1} + c_t*A' + f_{t-1}*B'     (A'=0.01*d*aw, B'=0.01*d*bw)
//   xx_{t+1} = Sum(sigma'_t) + ngb + c_{t+1}*SA' + f_t*SB'
//   f_t = 200*tanh(max(P(xx_t), 0)),  P's coeffs pre-scaled by -2*log2(e)
// Critical loop-carried chain: f_t -> xx_{t+1} (1 fma) -> activation -> f_{t+1}.
// sigma/reduce path depends only on f_{t-1} -> overlaps the activation.
// Two chains share each 16-lane DPP row (quad-interleaved); allreduce8 =
// quad_perm[1,0,3,2] + quad_perm[2,3,0,1] + row_ror:8. 1024 waves = 1/SIMD.

#define TT 2048
#define BB 8192

typedef float v2f __attribute__((ext_vector_type(2)));

__device__ __forceinline__ float dpp_add_x1(float z) {
    float o;
    asm("v_add_f32 %0, %1, %2 quad_perm:[1,0,3,2] row_mask:0xf bank_mask:0xf"
        : "=v"(o) : "v"(z), "v"(z));
    return o;
}
__device__ __forceinline__ float dpp_add_x2(float z) {
    float o;
    asm("v_add_f32 %0, %1, %2 quad_perm:[2,3,0,1] row_mask:0xf bank_mask:0xf"
        : "=v"(o) : "v"(z), "v"(z));
    return o;
}
__device__ __forceinline__ float dpp_add_r8(float z) {
    float o;
    asm("v_add_f32 %0, %1, %2 row_ror:8 row_mask:0xf bank_mask:0xf"
        : "=v"(o) : "v"(z), "v"(z));
    return o;
}
__device__ __forceinline__ float allreduce8(float z) {
    z = dpp_add_x1(z);
    z = dpp_add_x2(z);
    z = dpp_add_r8(z);
    return z;
}

// One step. sg-update first (independent of xx), activation second.
#define STEP(ccur, cnext, so, FIN, FOUT) do {                           \
    v2f f2 = { FIN, FIN };                                              \
    v2f c2 = { (ccur), (ccur) };                                        \
    sg0 = __builtin_elementwise_fma(d0, sg0,                            \
            __builtin_elementwise_fma(c2, A0, f2 * B0));                \
    sg1 = __builtin_elementwise_fma(d1, sg1,                            \
            __builtin_elementwise_fma(c2, A1, f2 * B1));                \
    sg2 = __builtin_elementwise_fma(d2, sg2,                            \
            __builtin_elementwise_fma(c2, A2, f2 * B2));                \
    sg3 = __builtin_elementwise_fma(d3, sg3,                            \
            __builtin_elementwise_fma(c2, A3, f2 * B3));                \
    v2f ss = (sg0 + sg1) + (sg2 + sg3);                                 \
    float Sr = allreduce8(ss.x + ss.y) + ngb01;                         \
    float base = fmaf((cnext), SAp, Sr);                                \
    float x2 = xx * xx;                                                 \
    float t1 = fmaf(k5, xx, k4);                                        \
    float t2 = fmaf(k3, xx, k2);                                        \
    float t3 = fmaf(k1, xx, k0);                                        \
    float pl = fmaf(t1, x2, t2);                                        \
    pl = fmaf(pl, x2, t3);                                              \
    pl = fminf(pl, 0.0f);            /* coeffs carry -2*log2e */        \
    float ee = __builtin_amdgcn_exp2f(pl);                              \
    FOUT = fmaf(ee, -200.0f, 200.0f) * __builtin_amdgcn_rcpf(1.0f + ee);\
    xx = fmaf(FOUT, SBp, base);                                         \
    if (h == 0) outp[obase + (so) * BB + chain] = FOUT;                 \
} while (0)

__global__ __launch_bounds__(256, 1) void frm_kernel(
    const float* __restrict__ cur, const float* __restrict__ fs0,
    const float* __restrict__ av,  const float* __restrict__ bv,
    const float* __restrict__ wv,  const float* __restrict__ dsv,
    const float* __restrict__ pcv, const float* __restrict__ gbv,
    float* __restrict__ outp)
{
    const int tid  = blockIdx.x * 256 + threadIdx.x;
    const int lane = threadIdx.x & 15;        // lane within DPP row
    const int row  = tid >> 4;                // 16-lane row id (0..4095)
    const int sub  = (lane >> 2) & 1;         // chain = quad parity
    const int chain = row * 2 + sub;          // batch index b (0..8191)
    const int h    = ((lane >> 3) << 2) | (lane & 3);  // state-group 0..7

    const int n0 = h * 8;                     // this lane's 8 state indices
    float wk0 = wv[n0+0], wk1 = wv[n0+1], wk2 = wv[n0+2], wk3 = wv[n0+3];
    float wk4 = wv[n0+4], wk5 = wv[n0+5], wk6 = wv[n0+6], wk7 = wv[n0+7];
    float dk0 = 1.0f-dsv[n0+0], dk1 = 1.0f-dsv[n0+1], dk2 = 1.0f-dsv[n0+2], dk3 = 1.0f-dsv[n0+3];
    float dk4 = 1.0f-dsv[n0+4], dk5 = 1.0f-dsv[n0+5], dk6 = 1.0f-dsv[n0+6], dk7 = 1.0f-dsv[n0+7];
    // 0.01 (the /MAX_I) folded into aw/bw here:
    float ak0 = 0.01f*av[n0+0]*wk0, ak1 = 0.01f*av[n0+1]*wk1;
    float ak2 = 0.01f*av[n0+2]*wk2, ak3 = 0.01f*av[n0+3]*wk3;
    float ak4 = 0.01f*av[n0+4]*wk4, ak5 = 0.01f*av[n0+5]*wk5;
    float ak6 = 0.01f*av[n0+6]*wk6, ak7 = 0.01f*av[n0+7]*wk7;
    float bk0 = 10.0f*bv[n0+0]*wk0, bk1 = 10.0f*bv[n0+1]*wk1;   // 1000*0.01
    float bk2 = 10.0f*bv[n0+2]*wk2, bk3 = 10.0f*bv[n0+3]*wk3;
    float bk4 = 10.0f*bv[n0+4]*wk4, bk5 = 10.0f*bv[n0+5]*wk5;
    float bk6 = 10.0f*bv[n0+6]*wk6, bk7 = 10.0f*bv[n0+7]*wk7;

    const v2f d0 = {dk0, dk1}, d1 = {dk2, dk3}, d2 = {dk4, dk5}, d3 = {dk6, dk7};
    const v2f A0 = {dk0*ak0, dk1*ak1}, A1 = {dk2*ak2, dk3*ak3};
    const v2f A2 = {dk4*ak4, dk5*ak5}, A3 = {dk6*ak6, dk7*ak7};
    const v2f B0 = {dk0*bk0, dk1*bk1}, B1 = {dk2*bk2, dk3*bk3};
    const v2f B2 = {dk4*bk4, dk5*bk5}, B3 = {dk6*bk6, dk7*bk7};

    const float SAp = allreduce8(((ak0+ak1)+(ak2+ak3)) + ((ak4+ak5)+(ak6+ak7)));
    const float SBp = allreduce8(((bk0+bk1)+(bk2+bk3)) + ((bk4+bk5)+(bk6+bk7)));

    // activation coeffs: squared, scaled by -2*log2(e) (fmax -> fmin flip)
    const float M = -2.8853900817779268f;
    const float k0 = M*pcv[0]*pcv[0], k1 = M*pcv[1]*pcv[1], k2 = M*pcv[2]*pcv[2];
    const float k3 = M*pcv[3]*pcv[3], k4 = M*pcv[4]*pcv[4], k5 = M*pcv[5]*pcv[5];
    const float ngb01 = -gbv[0] * 0.01f;

    float fA = fs0[chain];
    float fB;
    v2f sg0 = {0,0}, sg1 = {0,0}, sg2 = {0,0}, sg3 = {0,0};

    const float* cpt = cur + chain;

    // prefetch first 16 currents (distance-16 pipeline, two 8-wide banks)
    float P0 = cpt[0*BB], P1 = cpt[1*BB], P2 = cpt[2*BB], P3 = cpt[3*BB];
    float P4 = cpt[4*BB], P5 = cpt[5*BB], P6 = cpt[6*BB], P7 = cpt[7*BB];
    float Q0 = cpt[8*BB], Q1 = cpt[9*BB], Q2 = cpt[10*BB], Q3 = cpt[11*BB];
    float Q4 = cpt[12*BB], Q5 = cpt[13*BB], Q6 = cpt[14*BB], Q7 = cpt[15*BB];

    // xx_0 = 0.01*(c_0*SA + fs0*SB) + ngb  (sigma_{-1}=0; SAp/SBp carry 0.01)
    float xx = fmaf(fA, SBp, fmaf(P0, SAp, ngb01));

    int obase = 0;
    for (int t = 0; t + 32 <= TT; t += 16) {
        STEP(P0, P1, 0, fA, fB);  STEP(P1, P2, 1, fB, fA);
        STEP(P2, P3, 2, fA, fB);  STEP(P3, P4, 3, fB, fA);
        STEP(P4, P5, 4, fA, fB);  STEP(P5, P6, 5, fB, fA);
        STEP(P6, P7, 6, fA, fB);  STEP(P7, Q0, 7, fB, fA);
        P0 = cpt[obase + 16*BB]; P1 = cpt[obase + 17*BB];
        P2 = cpt[obase + 18*BB]; P3 = cpt[obase + 19*BB];
        P4 = cpt[obase + 20*BB]; P5 = cpt[obase + 21*BB];
        P6 = cpt[obase + 22*BB]; P7 = cpt[obase + 23*BB];
        STEP(Q0, Q1, 8, fA, fB);  STEP(Q1, Q2, 9, fB, fA);
        STEP(Q2, Q3, 10, fA, fB); STEP(Q3, Q4, 11, fB, fA);
        STEP(Q4, Q5, 12, fA, fB); STEP(Q5, Q6, 13, fB, fA);
        STEP(Q6, Q7, 14, fA, fB); STEP(Q7, P0, 15, fB, fA);
        Q0 = cpt[obase + 24*BB]; Q1 = cpt[obase + 25*BB];
        Q2 = cpt[obase + 26*BB]; Q3 = cpt[obase + 27*BB];
        Q4 = cpt[obase + 28*BB]; Q5 = cpt[obase + 29*BB];
        Q6 = cpt[obase + 30*BB]; Q7 = cpt[obase + 31*BB];
        obase += 16 * BB;
    }
    // epilogue: last 16 steps entirely from registers
    STEP(P0, P1, 0, fA, fB);  STEP(P1, P2, 1, fB, fA);
    STEP(P2, P3, 2, fA, fB);  STEP(P3, P4, 3, fB, fA);
    STEP(P4, P5, 4, fA, fB);  STEP(P5, P6, 5, fB, fA);
    STEP(P6, P7, 6, fA, fB);  STEP(P7, Q0, 7, fB, fA);
    STEP(Q0, Q1, 8, fA, fB);  STEP(Q1, Q2, 9, fB, fA);
    STEP(Q2, Q3, 10, fA, fB); STEP(Q3, Q4, 11, fB, fA);
    STEP(Q4, Q5, 12, fA, fB); STEP(Q5, Q6, 13, fB, fA);
    STEP(Q6, Q7, 14, fA, fB); STEP(Q7, 0.0f, 15, fB, fA);
}

extern "C" void kernel_launch(void* const* d_in, const int* in_sizes, int n_in,
                              void* d_out, int out_size, void* d_ws, size_t ws_size,
                              hipStream_t stream) {
    const float* cur = (const float*)d_in[0];
    const float* fs0 = (const float*)d_in[1];
    const float* a   = (const float*)d_in[2];
    const float* b   = (const float*)d_in[3];
    const float* w   = (const float*)d_in[4];
    const float* ds  = (const float*)d_in[5];
    const float* pc  = (const float*)d_in[6];
    const float* gb  = (const float*)d_in[7];
    float* out = (float*)d_out;

    const int threads = 256;
    const int grid = (BB * 8) / threads;   // 256 blocks = 1024 waves = 1/SIMD
    frm_kernel<<<grid, threads, 0, stream>>>(cur, fs0, a, b, w, ds, pc, gb, out);
}

// Round 7
// 174.328 us; speedup vs baseline: 1.8529x; 1.2363x over previous
//
#include <hip/hip_runtime.h>

// FiringRateModel, xx-recurrence, 8 lanes/chain, 8 states/lane (R5 core).
//   sigma'_t = d*sigma'_{t-1} + c_t*A' + f_{t-1}*B'   (A'=0.01*d*aw, B'=0.01*d*bw)
//   xx_{t+1} = Sum(sigma'_t) + ngb + c_{t+1}*SA' + f_t*SB'
//   f_t = 200*tanh(max(P(xx_t),0)), P coeffs pre-scaled by -2*log2(e)
// R6: no exec-masked per-step store. Lane h captures step (t0+h)'s f via
// cndmask; every 8 steps ALL lanes store unconditionally (1 store/8 steps,
// zero EXEC writes in the main loop).
// Two chains per 16-lane DPP row (quad-interleaved); allreduce8 = 3 fused
// DPP adds. 1024 waves = 1 wave/SIMD.

#define TT 2048
#define BB 8192

typedef float v2f __attribute__((ext_vector_type(2)));

__device__ __forceinline__ float dpp_add_x1(float z) {
    float o;
    asm("v_add_f32 %0, %1, %2 quad_perm:[1,0,3,2] row_mask:0xf bank_mask:0xf"
        : "=v"(o) : "v"(z), "v"(z));
    return o;
}
__device__ __forceinline__ float dpp_add_x2(float z) {
    float o;
    asm("v_add_f32 %0, %1, %2 quad_perm:[2,3,0,1] row_mask:0xf bank_mask:0xf"
        : "=v"(o) : "v"(z), "v"(z));
    return o;
}
__device__ __forceinline__ float dpp_add_r8(float z) {
    float o;
    asm("v_add_f32 %0, %1, %2 row_ror:8 row_mask:0xf bank_mask:0xf"
        : "=v"(o) : "v"(z), "v"(z));
    return o;
}
__device__ __forceinline__ float allreduce8(float z) {
    z = dpp_add_x1(z);
    z = dpp_add_x2(z);
    z = dpp_add_r8(z);
    return z;
}

// One step. sg-update (dep: f_{t-1}) first, activation (dep: xx_t) second;
// capture f into fkeep branchlessly when this lane's slot (h) == so&7.
#define STEP(ccur, cnext, so, FIN, FOUT) do {                           \
    v2f f2 = { FIN, FIN };                                              \
    v2f c2 = { (ccur), (ccur) };                                        \
    sg0 = __builtin_elementwise_fma(d0, sg0,                            \
            __builtin_elementwise_fma(c2, A0, f2 * B0));                \
    sg1 = __builtin_elementwise_fma(d1, sg1,                            \
            __builtin_elementwise_fma(c2, A1, f2 * B1));                \
    sg2 = __builtin_elementwise_fma(d2, sg2,                            \
            __builtin_elementwise_fma(c2, A2, f2 * B2));                \
    sg3 = __builtin_elementwise_fma(d3, sg3,                            \
            __builtin_elementwise_fma(c2, A3, f2 * B3));                \
    v2f ss = (sg0 + sg1) + (sg2 + sg3);                                 \
    float Sr = allreduce8(ss.x + ss.y) + ngb01;                         \
    float base = fmaf((cnext), SAp, Sr);                                \
    float x2 = xx * xx;                                                 \
    float t1 = fmaf(k5, xx, k4);                                        \
    float t2 = fmaf(k3, xx, k2);                                        \
    float t3 = fmaf(k1, xx, k0);                                        \
    float pl = fmaf(t1, x2, t2);                                        \
    pl = fmaf(pl, x2, t3);                                              \
    pl = fminf(pl, 0.0f);            /* coeffs carry -2*log2e */        \
    float ee = __builtin_amdgcn_exp2f(pl);                              \
    FOUT = fmaf(ee, -200.0f, 200.0f) * __builtin_amdgcn_rcpf(1.0f + ee);\
    xx = fmaf(FOUT, SBp, base);                                         \
    fkeep = (h == ((so) & 7)) ? FOUT : fkeep;                           \
} while (0)

// batched store: all 64 lanes, no exec mask; lane h writes step t0+h
#define FLUSH() do {                                                    \
    *optr = fkeep;                                                      \
    optr += 8 * BB;                                                     \
} while (0)

__global__ __launch_bounds__(256, 1) void frm_kernel(
    const float* __restrict__ cur, const float* __restrict__ fs0,
    const float* __restrict__ av,  const float* __restrict__ bv,
    const float* __restrict__ wv,  const float* __restrict__ dsv,
    const float* __restrict__ pcv, const float* __restrict__ gbv,
    float* __restrict__ outp)
{
    const int tid  = blockIdx.x * 256 + threadIdx.x;
    const int lane = threadIdx.x & 15;        // lane within DPP row
    const int row  = tid >> 4;                // 16-lane row id (0..4095)
    const int sub  = (lane >> 2) & 1;         // chain = quad parity
    const int chain = row * 2 + sub;          // batch index b (0..8191)
    const int h    = ((lane >> 3) << 2) | (lane & 3);  // state-group / store slot 0..7

    const int n0 = h * 8;                     // this lane's 8 state indices
    float wk0 = wv[n0+0], wk1 = wv[n0+1], wk2 = wv[n0+2], wk3 = wv[n0+3];
    float wk4 = wv[n0+4], wk5 = wv[n0+5], wk6 = wv[n0+6], wk7 = wv[n0+7];
    float dk0 = 1.0f-dsv[n0+0], dk1 = 1.0f-dsv[n0+1], dk2 = 1.0f-dsv[n0+2], dk3 = 1.0f-dsv[n0+3];
    float dk4 = 1.0f-dsv[n0+4], dk5 = 1.0f-dsv[n0+5], dk6 = 1.0f-dsv[n0+6], dk7 = 1.0f-dsv[n0+7];
    // 0.01 (the /MAX_I) folded into aw/bw:
    float ak0 = 0.01f*av[n0+0]*wk0, ak1 = 0.01f*av[n0+1]*wk1;
    float ak2 = 0.01f*av[n0+2]*wk2, ak3 = 0.01f*av[n0+3]*wk3;
    float ak4 = 0.01f*av[n0+4]*wk4, ak5 = 0.01f*av[n0+5]*wk5;
    float ak6 = 0.01f*av[n0+6]*wk6, ak7 = 0.01f*av[n0+7]*wk7;
    float bk0 = 10.0f*bv[n0+0]*wk0, bk1 = 10.0f*bv[n0+1]*wk1;   // 1000*0.01
    float bk2 = 10.0f*bv[n0+2]*wk2, bk3 = 10.0f*bv[n0+3]*wk3;
    float bk4 = 10.0f*bv[n0+4]*wk4, bk5 = 10.0f*bv[n0+5]*wk5;
    float bk6 = 10.0f*bv[n0+6]*wk6, bk7 = 10.0f*bv[n0+7]*wk7;

    const v2f d0 = {dk0, dk1}, d1 = {dk2, dk3}, d2 = {dk4, dk5}, d3 = {dk6, dk7};
    const v2f A0 = {dk0*ak0, dk1*ak1}, A1 = {dk2*ak2, dk3*ak3};
    const v2f A2 = {dk4*ak4, dk5*ak5}, A3 = {dk6*ak6, dk7*ak7};
    const v2f B0 = {dk0*bk0, dk1*bk1}, B1 = {dk2*bk2, dk3*bk3};
    const v2f B2 = {dk4*bk4, dk5*bk5}, B3 = {dk6*bk6, dk7*bk7};

    const float SAp = allreduce8(((ak0+ak1)+(ak2+ak3)) + ((ak4+ak5)+(ak6+ak7)));
    const float SBp = allreduce8(((bk0+bk1)+(bk2+bk3)) + ((bk4+bk5)+(bk6+bk7)));

    // activation coeffs: squared, scaled by -2*log2(e) (fmax -> fmin flip)
    const float M = -2.8853900817779268f;
    const float k0 = M*pcv[0]*pcv[0], k1 = M*pcv[1]*pcv[1], k2 = M*pcv[2]*pcv[2];
    const float k3 = M*pcv[3]*pcv[3], k4 = M*pcv[4]*pcv[4], k5 = M*pcv[5]*pcv[5];
    const float ngb01 = -gbv[0] * 0.01f;

    float fA = fs0[chain];
    float fB;
    float fkeep = 0.0f;
    v2f sg0 = {0,0}, sg1 = {0,0}, sg2 = {0,0}, sg3 = {0,0};

    const float* cpt = cur + chain;
    float* optr = outp + chain + h * BB;      // lane h's slot in the 8-step batch

    // prefetch first 16 currents (distance-16 pipeline, two 8-wide banks)
    float P0 = cpt[0*BB], P1 = cpt[1*BB], P2 = cpt[2*BB], P3 = cpt[3*BB];
    float P4 = cpt[4*BB], P5 = cpt[5*BB], P6 = cpt[6*BB], P7 = cpt[7*BB];
    float Q0 = cpt[8*BB], Q1 = cpt[9*BB], Q2 = cpt[10*BB], Q3 = cpt[11*BB];
    float Q4 = cpt[12*BB], Q5 = cpt[13*BB], Q6 = cpt[14*BB], Q7 = cpt[15*BB];

    // xx_0 = 0.01*(c_0*SA + fs0*SB) + ngb  (sigma_{-1}=0; SAp/SBp carry 0.01)
    float xx = fmaf(fA, SBp, fmaf(P0, SAp, ngb01));

    int obase = 0;
    for (int t = 0; t + 32 <= TT; t += 16) {
        STEP(P0, P1, 0, fA, fB);  STEP(P1, P2, 1, fB, fA);
        STEP(P2, P3, 2, fA, fB);  STEP(P3, P4, 3, fB, fA);
        STEP(P4, P5, 4, fA, fB);  STEP(P5, P6, 5, fB, fA);
        STEP(P6, P7, 6, fA, fB);  STEP(P7, Q0, 7, fB, fA);
        FLUSH();
        P0 = cpt[obase + 16*BB]; P1 = cpt[obase + 17*BB];
        P2 = cpt[obase + 18*BB]; P3 = cpt[obase + 19*BB];
        P4 = cpt[obase + 20*BB]; P5 = cpt[obase + 21*BB];
        P6 = cpt[obase + 22*BB]; P7 = cpt[obase + 23*BB];
        STEP(Q0, Q1, 8, fA, fB);  STEP(Q1, Q2, 9, fB, fA);
        STEP(Q2, Q3, 10, fA, fB); STEP(Q3, Q4, 11, fB, fA);
        STEP(Q4, Q5, 12, fA, fB); STEP(Q5, Q6, 13, fB, fA);
        STEP(Q6, Q7, 14, fA, fB); STEP(Q7, P0, 15, fB, fA);
        FLUSH();
        Q0 = cpt[obase + 24*BB]; Q1 = cpt[obase + 25*BB];
        Q2 = cpt[obase + 26*BB]; Q3 = cpt[obase + 27*BB];
        Q4 = cpt[obase + 28*BB]; Q5 = cpt[obase + 29*BB];
        Q6 = cpt[obase + 30*BB]; Q7 = cpt[obase + 31*BB];
        obase += 16 * BB;
    }
    // epilogue: last 16 steps entirely from registers
    STEP(P0, P1, 0, fA, fB);  STEP(P1, P2, 1, fB, fA);
    STEP(P2, P3, 2, fA, fB);  STEP(P3, P4, 3, fB, fA);
    STEP(P4, P5, 4, fA, fB);  STEP(P5, P6, 5, fB, fA);
    STEP(P6, P7, 6, fA, fB);  STEP(P7, Q0, 7, fB, fA);
    FLUSH();
    STEP(Q0, Q1, 8, fA, fB);  STEP(Q1, Q2, 9, fB, fA);
    STEP(Q2, Q3, 10, fA, fB); STEP(Q3, Q4, 11, fB, fA);
    STEP(Q4, Q5, 12, fA, fB); STEP(Q5, Q6, 13, fB, fA);
    STEP(Q6, Q7, 14, fA, fB); STEP(Q7, 0.0f, 15, fB, fA);
    FLUSH();
}

extern "C" void kernel_launch(void* const* d_in, const int* in_sizes, int n_in,
                              void* d_out, int out_size, void* d_ws, size_t ws_size,
                              hipStream_t stream) {
    const float* cur = (const float*)d_in[0];
    const float* fs0 = (const float*)d_in[1];
    const float* a   = (const float*)d_in[2];
    const float* b   = (const float*)d_in[3];
    const float* w   = (const float*)d_in[4];
    const float* ds  = (const float*)d_in[5];
    const float* pc  = (const float*)d_in[6];
    const float* gb  = (const float*)d_in[7];
    float* out = (float*)d_out;

    const int threads = 256;
    const int grid = (BB * 8) / threads;   // 256 blocks = 1024 waves = 1/SIMD
    frm_kernel<<<grid, threads, 0, stream>>>(cur, fs0, a, b, w, ds, pc, gb, out);
}

// Round 8
// 168.204 us; speedup vs baseline: 1.9204x; 1.0364x over previous
//
#include <hip/hip_runtime.h>

// FiringRateModel, xx-recurrence, 8 lanes/chain, 8 states/lane (R6 core).
//   sigma'_t = d*sigma'_{t-1} + c_t*A' + f_{t-1}*B'   (A'=0.01*d*aw, B'=0.01*d*bw)
//   y_{t+1}  = Sum(sigma'_t) + c_{t+1}*SA' + f_t*SB'      (y = 0.01*z)
//   f_t = 400*rcp(1+exp2(Q(y_t))) - 200,  Q = P shifted by ngb, coeffs
//         pre-scaled by -2*log2(e)  [== relu(200*tanh(P(x)))]
// R7: tanh finish fma-form; ngb shift-folded into poly coeffs; capture via
// bfi with precomputed lane masks. 1 store / 8 steps, zero EXEC writes.
// Two chains per 16-lane DPP row (quad-interleaved); allreduce8 = 3 fused
// DPP adds. 1024 waves = 1 wave/SIMD.

#define TT 2048
#define BB 8192

typedef float v2f __attribute__((ext_vector_type(2)));

__device__ __forceinline__ float dpp_add_x1(float z) {
    float o;
    asm("v_add_f32 %0, %1, %2 quad_perm:[1,0,3,2] row_mask:0xf bank_mask:0xf"
        : "=v"(o) : "v"(z), "v"(z));
    return o;
}
__device__ __forceinline__ float dpp_add_x2(float z) {
    float o;
    asm("v_add_f32 %0, %1, %2 quad_perm:[2,3,0,1] row_mask:0xf bank_mask:0xf"
        : "=v"(o) : "v"(z), "v"(z));
    return o;
}
__device__ __forceinline__ float dpp_add_r8(float z) {
    float o;
    asm("v_add_f32 %0, %1, %2 row_ror:8 row_mask:0xf bank_mask:0xf"
        : "=v"(o) : "v"(z), "v"(z));
    return o;
}
__device__ __forceinline__ float allreduce8(float z) {
    z = dpp_add_x1(z);
    z = dpp_add_x2(z);
    z = dpp_add_r8(z);
    return z;
}

// branchless capture: fkeep = mk ? FOUT : fkeep as v_bfi_b32
__device__ __forceinline__ float bfi_keep(unsigned mk, float nf, float of) {
    unsigned r = (__float_as_uint(nf) & mk) | (__float_as_uint(of) & ~mk);
    return __uint_as_float(r);
}

// One step. sg-update (dep: f_{t-1}) first, activation (dep: y_t) second.
#define STEP(ccur, cnext, so, FIN, FOUT) do {                           \
    v2f f2 = { FIN, FIN };                                              \
    v2f c2 = { (ccur), (ccur) };                                        \
    sg0 = __builtin_elementwise_fma(d0, sg0,                            \
            __builtin_elementwise_fma(c2, A0, f2 * B0));                \
    sg1 = __builtin_elementwise_fma(d1, sg1,                            \
            __builtin_elementwise_fma(c2, A1, f2 * B1));                \
    sg2 = __builtin_elementwise_fma(d2, sg2,                            \
            __builtin_elementwise_fma(c2, A2, f2 * B2));                \
    sg3 = __builtin_elementwise_fma(d3, sg3,                            \
            __builtin_elementwise_fma(c2, A3, f2 * B3));                \
    v2f ss = (sg0 + sg1) + (sg2 + sg3);                                 \
    float Sr = allreduce8(ss.x + ss.y);                                 \
    float base = fmaf((cnext), SAp, Sr);                                \
    float x2 = yy * yy;                                                 \
    float t1 = fmaf(q5, yy, q4);                                        \
    float t2 = fmaf(q3, yy, q2);                                        \
    float t3 = fmaf(q1, yy, q0);                                        \
    float pl = fmaf(t1, x2, t2);                                        \
    pl = fmaf(pl, x2, t3);                                              \
    pl = fminf(pl, 0.0f);            /* coeffs carry -2*log2e */        \
    float ee = __builtin_amdgcn_exp2f(pl);                              \
    FOUT = fmaf(__builtin_amdgcn_rcpf(1.0f + ee), 400.0f, -200.0f);     \
    yy = fmaf(FOUT, SBp, base);                                         \
    fkeep = bfi_keep(msk[(so) & 7], FOUT, fkeep);                       \
} while (0)

// batched store: all 64 lanes, no exec mask; lane h writes step t0+h
#define FLUSH() do {                                                    \
    *optr = fkeep;                                                      \
    optr += 8 * BB;                                                     \
} while (0)

__global__ __launch_bounds__(256, 1) void frm_kernel(
    const float* __restrict__ cur, const float* __restrict__ fs0,
    const float* __restrict__ av,  const float* __restrict__ bv,
    const float* __restrict__ wv,  const float* __restrict__ dsv,
    const float* __restrict__ pcv, const float* __restrict__ gbv,
    float* __restrict__ outp)
{
    const int tid  = blockIdx.x * 256 + threadIdx.x;
    const int lane = threadIdx.x & 15;        // lane within DPP row
    const int row  = tid >> 4;                // 16-lane row id (0..4095)
    const int sub  = (lane >> 2) & 1;         // chain = quad parity
    const int chain = row * 2 + sub;          // batch index b (0..8191)
    const int h    = ((lane >> 3) << 2) | (lane & 3);  // state-group / store slot 0..7

    const int n0 = h * 8;                     // this lane's 8 state indices
    float wk0 = wv[n0+0], wk1 = wv[n0+1], wk2 = wv[n0+2], wk3 = wv[n0+3];
    float wk4 = wv[n0+4], wk5 = wv[n0+5], wk6 = wv[n0+6], wk7 = wv[n0+7];
    float dk0 = 1.0f-dsv[n0+0], dk1 = 1.0f-dsv[n0+1], dk2 = 1.0f-dsv[n0+2], dk3 = 1.0f-dsv[n0+3];
    float dk4 = 1.0f-dsv[n0+4], dk5 = 1.0f-dsv[n0+5], dk6 = 1.0f-dsv[n0+6], dk7 = 1.0f-dsv[n0+7];
    // 0.01 (the /MAX_I) folded into aw/bw:
    float ak0 = 0.01f*av[n0+0]*wk0, ak1 = 0.01f*av[n0+1]*wk1;
    float ak2 = 0.01f*av[n0+2]*wk2, ak3 = 0.01f*av[n0+3]*wk3;
    float ak4 = 0.01f*av[n0+4]*wk4, ak5 = 0.01f*av[n0+5]*wk5;
    float ak6 = 0.01f*av[n0+6]*wk6, ak7 = 0.01f*av[n0+7]*wk7;
    float bk0 = 10.0f*bv[n0+0]*wk0, bk1 = 10.0f*bv[n0+1]*wk1;   // 1000*0.01
    float bk2 = 10.0f*bv[n0+2]*wk2, bk3 = 10.0f*bv[n0+3]*wk3;
    float bk4 = 10.0f*bv[n0+4]*wk4, bk5 = 10.0f*bv[n0+5]*wk5;
    float bk6 = 10.0f*bv[n0+6]*wk6, bk7 = 10.0f*bv[n0+7]*wk7;

    const v2f d0 = {dk0, dk1}, d1 = {dk2, dk3}, d2 = {dk4, dk5}, d3 = {dk6, dk7};
    const v2f A0 = {dk0*ak0, dk1*ak1}, A1 = {dk2*ak2, dk3*ak3};
    const v2f A2 = {dk4*ak4, dk5*ak5}, A3 = {dk6*ak6, dk7*ak7};
    const v2f B0 = {dk0*bk0, dk1*bk1}, B1 = {dk2*bk2, dk3*bk3};
    const v2f B2 = {dk4*bk4, dk5*bk5}, B3 = {dk6*bk6, dk7*bk7};

    const float SAp = allreduce8(((ak0+ak1)+(ak2+ak3)) + ((ak4+ak5)+(ak6+ak7)));
    const float SBp = allreduce8(((bk0+bk1)+(bk2+bk3)) + ((bk4+bk5)+(bk6+bk7)));

    // poly coeffs: squared, scaled by -2*log2(e)
    const float M = -2.8853900817779268f;
    float c0 = M*pcv[0]*pcv[0], c1 = M*pcv[1]*pcv[1], c2c = M*pcv[2]*pcv[2];
    float c3 = M*pcv[3]*pcv[3], c4 = M*pcv[4]*pcv[4], c5 = M*pcv[5]*pcv[5];
    // shift-fold: Q(y) = P(y + s), s = -gb*0.01, via 5 rounds of synthetic
    // division (Horner shift). After round j, cj..c5 hold the shifted tail.
    const float s = -gbv[0] * 0.01f;
    {
        // round 1: fold into c0..c5
        c4 = fmaf(c5, s, c4); c3 = fmaf(c4, s, c3); c2c = fmaf(c3, s, c2c);
        c1 = fmaf(c2c, s, c1); c0 = fmaf(c1, s, c0);
        // round 2: c1..c5
        c4 = fmaf(c5, s, c4); c3 = fmaf(c4, s, c3); c2c = fmaf(c3, s, c2c);
        c1 = fmaf(c2c, s, c1);
        // round 3: c2..c5
        c4 = fmaf(c5, s, c4); c3 = fmaf(c4, s, c3); c2c = fmaf(c3, s, c2c);
        // round 4: c3..c5
        c4 = fmaf(c5, s, c4); c3 = fmaf(c4, s, c3);
        // round 5: c4..c5
        c4 = fmaf(c5, s, c4);
    }
    const float q0 = c0, q1 = c1, q2 = c2c, q3 = c3, q4 = c4, q5 = c5;

    // capture masks: all-ones when h == k (v_bfi operand)
    unsigned msk[8];
#pragma unroll
    for (int k = 0; k < 8; ++k) msk[k] = (h == k) ? 0xFFFFFFFFu : 0u;

    float fA = fs0[chain];
    float fB;
    float fkeep = 0.0f;
    v2f sg0 = {0,0}, sg1 = {0,0}, sg2 = {0,0}, sg3 = {0,0};

    const float* cpt = cur + chain;
    float* optr = outp + chain + h * BB;      // lane h's slot in the 8-step batch

    // prefetch first 16 currents (distance-16 pipeline, two 8-wide banks)
    float P0 = cpt[0*BB], P1 = cpt[1*BB], P2 = cpt[2*BB], P3 = cpt[3*BB];
    float P4 = cpt[4*BB], P5 = cpt[5*BB], P6 = cpt[6*BB], P7 = cpt[7*BB];
    float Q0 = cpt[8*BB], Q1 = cpt[9*BB], Q2 = cpt[10*BB], Q3 = cpt[11*BB];
    float Q4 = cpt[12*BB], Q5 = cpt[13*BB], Q6 = cpt[14*BB], Q7 = cpt[15*BB];

    // y_0 = 0.01*(c_0*SA + fs0*SB)  (sigma_{-1}=0; SAp/SBp carry the 0.01)
    float yy = fmaf(fA, SBp, P0 * SAp);

    int obase = 0;
    for (int t = 0; t + 32 <= TT; t += 16) {
        STEP(P0, P1, 0, fA, fB);  STEP(P1, P2, 1, fB, fA);
        STEP(P2, P3, 2, fA, fB);  STEP(P3, P4, 3, fB, fA);
        STEP(P4, P5, 4, fA, fB);  STEP(P5, P6, 5, fB, fA);
        STEP(P6, P7, 6, fA, fB);  STEP(P7, Q0, 7, fB, fA);
        FLUSH();
        P0 = cpt[obase + 16*BB]; P1 = cpt[obase + 17*BB];
        P2 = cpt[obase + 18*BB]; P3 = cpt[obase + 19*BB];
        P4 = cpt[obase + 20*BB]; P5 = cpt[obase + 21*BB];
        P6 = cpt[obase + 22*BB]; P7 = cpt[obase + 23*BB];
        STEP(Q0, Q1, 8, fA, fB);  STEP(Q1, Q2, 9, fB, fA);
        STEP(Q2, Q3, 10, fA, fB); STEP(Q3, Q4, 11, fB, fA);
        STEP(Q4, Q5, 12, fA, fB); STEP(Q5, Q6, 13, fB, fA);
        STEP(Q6, Q7, 14, fA, fB); STEP(Q7, P0, 15, fB, fA);
        FLUSH();
        Q0 = cpt[obase + 24*BB]; Q1 = cpt[obase + 25*BB];
        Q2 = cpt[obase + 26*BB]; Q3 = cpt[obase + 27*BB];
        Q4 = cpt[obase + 28*BB]; Q5 = cpt[obase + 29*BB];
        Q6 = cpt[obase + 30*BB]; Q7 = cpt[obase + 31*BB];
        obase += 16 * BB;
    }
    // epilogue: last 16 steps entirely from registers
    STEP(P0, P1, 0, fA, fB);  STEP(P1, P2, 1, fB, fA);
    STEP(P2, P3, 2, fA, fB);  STEP(P3, P4, 3, fB, fA);
    STEP(P4, P5, 4, fA, fB);  STEP(P5, P6, 5, fB, fA);
    STEP(P6, P7, 6, fA, fB);  STEP(P7, Q0, 7, fB, fA);
    FLUSH();
    STEP(Q0, Q1, 8, fA, fB);  STEP(Q1, Q2, 9, fB, fA);
    STEP(Q2, Q3, 10, fA, fB); STEP(Q3, Q4, 11, fB, fA);
    STEP(Q4, Q5, 12, fA, fB); STEP(Q5, Q6, 13, fB, fA);
    STEP(Q6, Q7, 14, fA, fB); STEP(Q7, 0.0f, 15, fB, fA);
    FLUSH();
}

extern "C" void kernel_launch(void* const* d_in, const int* in_sizes, int n_in,
                              void* d_out, int out_size, void* d_ws, size_t ws_size,
                              hipStream_t stream) {
    const float* cur = (const float*)d_in[0];
    const float* fs0 = (const float*)d_in[1];
    const float* a   = (const float*)d_in[2];
    const float* b   = (const float*)d_in[3];
    const float* w   = (const float*)d_in[4];
    const float* ds  = (const float*)d_in[5];
    const float* pc  = (const float*)d_in[6];
    const float* gb  = (const float*)d_in[7];
    float* out = (float*)d_out;

    const int threads = 256;
    const int grid = (BB * 8) / threads;   // 256 blocks = 1024 waves = 1/SIMD
    frm_kernel<<<grid, threads, 0, stream>>>(cur, fs0, a, b, w, ds, pc, gb, out);
}